// Round 3
// baseline (3903.068 us; speedup 1.0000x reference)
//
#include <hip/hip_runtime.h>
#include <hip/hip_bf16.h>

#define N_NODES 50000
#define N_EDGES 800000
#define DIM 96
#define CH 24  // DIM/4 float4 chunks per row

// ---------------- dtype detection (on-device, graph-capture safe) ----------------
// flags[0] = h is bf16, flags[1] = W/b are bf16, flags[2] = indices are int64
// Output dtype follows flags[0] (harness bf16-ifies all-or-nothing).

__global__ void detect_kernel(const unsigned* __restrict__ hw,
                              const unsigned* __restrict__ ww,
                              const unsigned* __restrict__ sw,
                              int* __restrict__ flags) {
    int t = threadIdx.x;
    if (t == 0 || t == 1) {
        const unsigned* p = (t == 0) ? hw : ww;
        int good = 0;
        for (int i = 0; i < 128; ++i) {
            unsigned w = p[i];
            unsigned lo = w & 0xFFFFu, hi = w >> 16;
            unsigned e0 = (lo >> 7) & 0xFF, e1 = (hi >> 7) & 0xFF;
            if (lo == 0 || (e0 >= 100 && e0 <= 140)) ++good;
            if (hi == 0 || (e1 >= 100 && e1 <= 140)) ++good;
        }
        flags[t] = (good >= 226) ? 1 : 0;  // bf16 scores ~256/256, fp32 ~148/256
    } else if (t == 2) {
        int zeros = 0;
        for (int i = 0; i < 64; ++i)
            if (sw[2 * i + 1] == 0u) ++zeros;
        flags[2] = (zeros >= 60) ? 1 : 0;  // int64 high words all zero
    }
}

__device__ __forceinline__ int load_idx(const int* __restrict__ p, int e, int is64) {
    return p[is64 ? (e << 1) : e];  // little-endian low word of int64
}

// ---------------- degree + norm ----------------

__global__ __launch_bounds__(256) void deg_kernel(const int* __restrict__ src,
                                                  const int* __restrict__ dst,
                                                  int* __restrict__ degS,
                                                  int* __restrict__ degD,
                                                  const int* __restrict__ flags) {
    int is64 = flags[2];
    int e = blockIdx.x * 256 + threadIdx.x;
    if (e < N_EDGES) {
        atomicAdd(&degS[load_idx(src, e, is64)], 1);
        atomicAdd(&degD[load_idx(dst, e, is64)], 1);
    }
}

__global__ __launch_bounds__(256) void norm_kernel(const int* __restrict__ degS,
                                                   const int* __restrict__ degD,
                                                   float* __restrict__ normS,
                                                   float* __restrict__ normD) {
    int i = blockIdx.x * 256 + threadIdx.x;
    if (i < N_NODES) {
        normS[i] = rsqrtf((float)max(degS[i], 1));
        normD[i] = rsqrtf((float)max(degD[i], 1));
    }
}

// ---------------- layer-0 input -> fp32 (dtype-branching) ----------------

__global__ __launch_bounds__(256) void cvt_kernel(const void* __restrict__ h,
                                                  float* __restrict__ out,
                                                  const int* __restrict__ flags) {
    int i = blockIdx.x * 256 + threadIdx.x;
    if (i >= N_NODES * DIM) return;
    if (flags[0])
        out[i] = __bfloat162float(((const __hip_bfloat16*)h)[i]);
    else
        out[i] = ((const float*)h)[i];
}

// ---------------- edge scatter: B[dst] += x[src] * normS[src] ----------------

__global__ __launch_bounds__(256) void scatter_kernel(const float* __restrict__ x,
                                                      const int* __restrict__ src,
                                                      const int* __restrict__ dst,
                                                      const float* __restrict__ normS,
                                                      float* __restrict__ B,
                                                      const int* __restrict__ flags) {
    int is64 = flags[2];
    int t = blockIdx.x * 256 + threadIdx.x;
    if (t >= N_EDGES * CH) return;
    int e = t / CH;
    int c = t - e * CH;
    int s = load_idx(src, e, is64);
    int d = load_idx(dst, e, is64);
    float ns = normS[s];
    float4 v = ((const float4*)x)[s * CH + c];
    float* o = B + (size_t)d * DIM + (size_t)c * 4;
    atomicAdd(o + 0, v.x * ns);
    atomicAdd(o + 1, v.y * ns);
    atomicAdd(o + 2, v.z * ns);
    atomicAdd(o + 3, v.w * ns);
}

// ---------------- GEMM: out = relu((B * normD_row) @ W + b) ----------------
// 64-row tile per block, W staged in LDS (dtype-branching), 2 rows x 12 cols
// per thread. Bs padded to 97 floats/row -> conflict-free column reads.
// LAST layer: output dtype follows flags[0] (fp32 vs bf16).

template <bool LAST>
__global__ __launch_bounds__(256) void gemm_relu(const float* __restrict__ M,
                                                 const float* __restrict__ normD,
                                                 const void* __restrict__ W,
                                                 const void* __restrict__ bias,
                                                 float* __restrict__ outF,
                                                 void* __restrict__ outLast,
                                                 const int* __restrict__ flags) {
    __shared__ float Ws[DIM * DIM];      // 36864 B
    __shared__ float Bs[64][DIM + 1];    // 24832 B
    __shared__ float bs[DIM];

    int wbf = flags[1];
    if (wbf) {
        for (int i = threadIdx.x; i < DIM * DIM; i += 256)
            Ws[i] = __bfloat162float(((const __hip_bfloat16*)W)[i]);
        if (threadIdx.x < DIM)
            bs[threadIdx.x] = __bfloat162float(((const __hip_bfloat16*)bias)[threadIdx.x]);
    } else {
        for (int i = threadIdx.x; i < DIM * DIM; i += 256)
            Ws[i] = ((const float*)W)[i];
        if (threadIdx.x < DIM)
            bs[threadIdx.x] = ((const float*)bias)[threadIdx.x];
    }

    int row0 = blockIdx.x * 64;
    for (int i = threadIdx.x; i < 64 * CH; i += 256) {
        int r = i / CH;
        int c4 = i - r * CH;
        int gr = row0 + r;
        float4 v = make_float4(0.f, 0.f, 0.f, 0.f);
        float nd = 0.f;
        if (gr < N_NODES) {
            v = ((const float4*)M)[gr * CH + c4];
            nd = normD[gr];
        }
        float* bp = &Bs[r][c4 * 4];
        bp[0] = v.x * nd;
        bp[1] = v.y * nd;
        bp[2] = v.z * nd;
        bp[3] = v.w * nd;
    }
    __syncthreads();

    int cg = threadIdx.x & 7;   // 8 col-groups of 12 cols
    int rg = threadIdx.x >> 3;  // 32 row-groups of 2 rows
    int r0 = rg * 2;
    int c0 = cg * 12;

    float acc0[12], acc1[12];
#pragma unroll
    for (int j = 0; j < 12; ++j) { acc0[j] = 0.f; acc1[j] = 0.f; }

    for (int k = 0; k < DIM; ++k) {
        float a0 = Bs[r0][k];
        float a1 = Bs[r0 + 1][k];
        const float4* w4 = (const float4*)&Ws[k * DIM + c0];
#pragma unroll
        for (int j4 = 0; j4 < 3; ++j4) {
            float4 w = w4[j4];
            acc0[j4 * 4 + 0] += a0 * w.x;
            acc0[j4 * 4 + 1] += a0 * w.y;
            acc0[j4 * 4 + 2] += a0 * w.z;
            acc0[j4 * 4 + 3] += a0 * w.w;
            acc1[j4 * 4 + 0] += a1 * w.x;
            acc1[j4 * 4 + 1] += a1 * w.y;
            acc1[j4 * 4 + 2] += a1 * w.z;
            acc1[j4 * 4 + 3] += a1 * w.w;
        }
    }

    int hbf = flags[0];
#pragma unroll
    for (int rr = 0; rr < 2; ++rr) {
        int gr = row0 + r0 + rr;
        if (gr >= N_NODES) continue;
        const float* accp = rr ? acc1 : acc0;
#pragma unroll
        for (int j = 0; j < 12; ++j) {
            float v = fmaxf(accp[j] + bs[c0 + j], 0.f);
            size_t idx = (size_t)gr * DIM + c0 + j;
            if (LAST) {
                if (hbf)
                    ((__hip_bfloat16*)outLast)[idx] = __float2bfloat16(v);
                else
                    ((float*)outLast)[idx] = v;
            } else {
                outF[idx] = v;
            }
        }
    }
}

// ---------------- host launch ----------------

extern "C" void kernel_launch(void* const* d_in, const int* in_sizes, int n_in,
                              void* d_out, int out_size, void* d_ws, size_t ws_size,
                              hipStream_t stream) {
    const void* h = d_in[0];
    const int* src = (const int*)d_in[1];
    const int* dst = (const int*)d_in[2];
    const void* Wt[3] = {d_in[3], d_in[5], d_in[7]};
    const void* bt[3] = {d_in[4], d_in[6], d_in[8]};

    // workspace layout
    int* flags = (int*)d_ws;                       // 4 ints
    int* degS = flags + 4;
    int* degD = degS + N_NODES;
    float* normS = (float*)(degD + N_NODES);
    float* normD = normS + N_NODES;
    float* A = normD + N_NODES;                    // [N, D] fp32 layer activations
    float* Bm = A + (size_t)N_NODES * DIM;         // [N, D] fp32 aggregate buffer

    detect_kernel<<<1, 64, 0, stream>>>((const unsigned*)h, (const unsigned*)d_in[3],
                                        (const unsigned*)src, flags);

    hipMemsetAsync(degS, 0, 2 * N_NODES * sizeof(int), stream);
    deg_kernel<<<(N_EDGES + 255) / 256, 256, 0, stream>>>(src, dst, degS, degD, flags);
    norm_kernel<<<(N_NODES + 255) / 256, 256, 0, stream>>>(degS, degD, normS, normD);

    cvt_kernel<<<(N_NODES * DIM + 255) / 256, 256, 0, stream>>>(h, A, flags);

    const int scatter_grid = (N_EDGES * CH + 255) / 256;
    const int gemm_grid = (N_NODES + 63) / 64;

    for (int l = 0; l < 3; ++l) {
        hipMemsetAsync(Bm, 0, (size_t)N_NODES * DIM * sizeof(float), stream);
        scatter_kernel<<<scatter_grid, 256, 0, stream>>>(A, src, dst, normS, Bm, flags);
        if (l < 2)
            gemm_relu<false><<<gemm_grid, 256, 0, stream>>>(Bm, normD, Wt[l], bt[l], A, nullptr, flags);
        else
            gemm_relu<true><<<gemm_grid, 256, 0, stream>>>(Bm, normD, Wt[l], bt[l], nullptr,
                                                           d_out, flags);
    }
}

// Round 4
// 575.942 us; speedup vs baseline: 6.7768x; 6.7768x over previous
//
#include <hip/hip_runtime.h>
#include <hip/hip_bf16.h>

#define N_NODES 50000
#define N_EDGES 800000
#define DIM 96
#define CH 24  // DIM/4 float4 chunks per row

// ---------------- dtype detection (on-device, graph-capture safe) ----------------
// flags[0] = h is bf16, flags[1] = W/b are bf16, flags[2] = indices are int64
// Output dtype follows flags[0]. (Measured R3: this problem is fp32 + int64.)

__global__ void detect_kernel(const unsigned* __restrict__ hw,
                              const unsigned* __restrict__ ww,
                              const unsigned* __restrict__ sw,
                              int* __restrict__ flags) {
    int t = threadIdx.x;
    if (t == 0 || t == 1) {
        const unsigned* p = (t == 0) ? hw : ww;
        int good = 0;
        for (int i = 0; i < 128; ++i) {
            unsigned w = p[i];
            unsigned lo = w & 0xFFFFu, hi = w >> 16;
            unsigned e0 = (lo >> 7) & 0xFF, e1 = (hi >> 7) & 0xFF;
            if (lo == 0 || (e0 >= 100 && e0 <= 140)) ++good;
            if (hi == 0 || (e1 >= 100 && e1 <= 140)) ++good;
        }
        flags[t] = (good >= 226) ? 1 : 0;
    } else if (t == 2) {
        int zeros = 0;
        for (int i = 0; i < 64; ++i)
            if (sw[2 * i + 1] == 0u) ++zeros;
        flags[2] = (zeros >= 60) ? 1 : 0;
    }
}

__device__ __forceinline__ int load_idx(const int* __restrict__ p, int e, int is64) {
    return p[is64 ? (e << 1) : e];
}

// ---------------- degrees ----------------

__global__ __launch_bounds__(256) void deg_kernel(const int* __restrict__ src,
                                                  const int* __restrict__ dst,
                                                  int* __restrict__ degS,
                                                  int* __restrict__ degD,
                                                  const int* __restrict__ flags) {
    int is64 = flags[2];
    int e = blockIdx.x * 256 + threadIdx.x;
    if (e < N_EDGES) {
        atomicAdd(&degS[load_idx(src, e, is64)], 1);
        atomicAdd(&degD[load_idx(dst, e, is64)], 1);
    }
}

__global__ __launch_bounds__(256) void norm_kernel(const int* __restrict__ degS,
                                                   const int* __restrict__ degD,
                                                   float* __restrict__ normS,
                                                   float* __restrict__ normD) {
    int i = blockIdx.x * 256 + threadIdx.x;
    if (i < N_NODES) {
        normS[i] = rsqrtf((float)max(degS[i], 1));
        normD[i] = rsqrtf((float)max(degD[i], 1));
    }
}

// ---------------- CSR build: exclusive scan of degD -> rowptr ----------------
// single block, 1024 threads, 49 elems/thread; Hillis-Steele over LDS.

__global__ __launch_bounds__(1024) void scan_kernel(const int* __restrict__ degD,
                                                    int* __restrict__ rowptr) {
    __shared__ int sums[1024];
    const int CHUNK = (N_NODES + 1023) / 1024;  // 49
    int tid = threadIdx.x;
    int base = tid * CHUNK;
    int s = 0;
    for (int i = 0; i < CHUNK; ++i) {
        int idx = base + i;
        if (idx < N_NODES) s += degD[idx];
    }
    sums[tid] = s;
    __syncthreads();
    for (int off = 1; off < 1024; off <<= 1) {
        int v = (tid >= off) ? sums[tid - off] : 0;
        __syncthreads();
        sums[tid] += v;
        __syncthreads();
    }
    int run = (tid == 0) ? 0 : sums[tid - 1];
    for (int i = 0; i < CHUNK; ++i) {
        int idx = base + i;
        if (idx < N_NODES) { rowptr[idx] = run; run += degD[idx]; }
    }
    if (tid == 1023) rowptr[N_NODES] = N_EDGES;
}

// bucket-place: esrc[rowptr[dst]+slot] = src  (1 int atomic per edge)

__global__ __launch_bounds__(256) void bucket_kernel(const int* __restrict__ src,
                                                     const int* __restrict__ dst,
                                                     const int* __restrict__ rowptr,
                                                     int* __restrict__ cnt,
                                                     int* __restrict__ esrc,
                                                     const int* __restrict__ flags) {
    int is64 = flags[2];
    int e = blockIdx.x * 256 + threadIdx.x;
    if (e < N_EDGES) {
        int d = load_idx(dst, e, is64);
        int s = load_idx(src, e, is64);
        int pos = rowptr[d] + atomicAdd(&cnt[d], 1);
        esrc[pos] = s;
    }
}

// ---------------- layer-0 input -> fp32, pre-scaled by normS ----------------

__global__ __launch_bounds__(256) void cvt_kernel(const void* __restrict__ h,
                                                  const float* __restrict__ normS,
                                                  float* __restrict__ out,
                                                  const int* __restrict__ flags) {
    int i = blockIdx.x * 256 + threadIdx.x;
    if (i >= N_NODES * DIM) return;
    float v = flags[0] ? __bfloat162float(((const __hip_bfloat16*)h)[i])
                       : ((const float*)h)[i];
    out[i] = v * normS[i / DIM];
}

// ---------------- gather: B[n] = normD[n] * sum_{e:dst=n} xs[esrc[e]] ----------------
// 24 consecutive threads per node, one float4 chunk each; coalesced 384B row reads.

__global__ __launch_bounds__(256) void gather_kernel(const float* __restrict__ xs,
                                                     const int* __restrict__ rowptr,
                                                     const int* __restrict__ esrc,
                                                     const float* __restrict__ normD,
                                                     float* __restrict__ B) {
    int g = blockIdx.x * 256 + threadIdx.x;
    if (g >= N_NODES * CH) return;
    int n = g / CH;
    int c = g - n * CH;
    int beg = rowptr[n], end = rowptr[n + 1];
    float4 acc = make_float4(0.f, 0.f, 0.f, 0.f);
    for (int k = beg; k < end; ++k) {
        int s = esrc[k];
        float4 v = ((const float4*)xs)[s * CH + c];
        acc.x += v.x; acc.y += v.y; acc.z += v.z; acc.w += v.w;
    }
    float nd = normD[n];
    acc.x *= nd; acc.y *= nd; acc.z *= nd; acc.w *= nd;
    ((float4*)B)[g] = acc;
}

// ---------------- GEMM: t = relu(B @ W + b); non-last: A = t*normS; last: out ----------------

template <bool LAST>
__global__ __launch_bounds__(256) void gemm_relu(const float* __restrict__ M,
                                                 const float* __restrict__ normS,
                                                 const void* __restrict__ W,
                                                 const void* __restrict__ bias,
                                                 float* __restrict__ outF,
                                                 void* __restrict__ outLast,
                                                 const int* __restrict__ flags) {
    __shared__ float Ws[DIM * DIM];
    __shared__ float Bs[64][DIM + 1];
    __shared__ float bs[DIM];

    int wbf = flags[1];
    if (wbf) {
        for (int i = threadIdx.x; i < DIM * DIM; i += 256)
            Ws[i] = __bfloat162float(((const __hip_bfloat16*)W)[i]);
        if (threadIdx.x < DIM)
            bs[threadIdx.x] = __bfloat162float(((const __hip_bfloat16*)bias)[threadIdx.x]);
    } else {
        for (int i = threadIdx.x; i < DIM * DIM; i += 256)
            Ws[i] = ((const float*)W)[i];
        if (threadIdx.x < DIM)
            bs[threadIdx.x] = ((const float*)bias)[threadIdx.x];
    }

    int row0 = blockIdx.x * 64;
    for (int i = threadIdx.x; i < 64 * CH; i += 256) {
        int r = i / CH;
        int c4 = i - r * CH;
        int gr = row0 + r;
        float4 v = make_float4(0.f, 0.f, 0.f, 0.f);
        if (gr < N_NODES) v = ((const float4*)M)[gr * CH + c4];
        float* bp = &Bs[r][c4 * 4];
        bp[0] = v.x; bp[1] = v.y; bp[2] = v.z; bp[3] = v.w;
    }
    __syncthreads();

    int cg = threadIdx.x & 7;
    int rg = threadIdx.x >> 3;
    int r0 = rg * 2;
    int c0 = cg * 12;

    float acc0[12], acc1[12];
#pragma unroll
    for (int j = 0; j < 12; ++j) { acc0[j] = 0.f; acc1[j] = 0.f; }

    for (int k = 0; k < DIM; ++k) {
        float a0 = Bs[r0][k];
        float a1 = Bs[r0 + 1][k];
        const float4* w4 = (const float4*)&Ws[k * DIM + c0];
#pragma unroll
        for (int j4 = 0; j4 < 3; ++j4) {
            float4 w = w4[j4];
            acc0[j4 * 4 + 0] += a0 * w.x;
            acc0[j4 * 4 + 1] += a0 * w.y;
            acc0[j4 * 4 + 2] += a0 * w.z;
            acc0[j4 * 4 + 3] += a0 * w.w;
            acc1[j4 * 4 + 0] += a1 * w.x;
            acc1[j4 * 4 + 1] += a1 * w.y;
            acc1[j4 * 4 + 2] += a1 * w.z;
            acc1[j4 * 4 + 3] += a1 * w.w;
        }
    }

    int hbf = flags[0];
#pragma unroll
    for (int rr = 0; rr < 2; ++rr) {
        int gr = row0 + r0 + rr;
        if (gr >= N_NODES) continue;
        const float* accp = rr ? acc1 : acc0;
        float ns = LAST ? 1.f : normS[gr];
#pragma unroll
        for (int j = 0; j < 12; ++j) {
            float v = fmaxf(accp[j] + bs[c0 + j], 0.f);
            size_t idx = (size_t)gr * DIM + c0 + j;
            if (LAST) {
                if (hbf)
                    ((__hip_bfloat16*)outLast)[idx] = __float2bfloat16(v);
                else
                    ((float*)outLast)[idx] = v;
            } else {
                outF[idx] = v * ns;
            }
        }
    }
}

// ---------------- host launch ----------------

extern "C" void kernel_launch(void* const* d_in, const int* in_sizes, int n_in,
                              void* d_out, int out_size, void* d_ws, size_t ws_size,
                              hipStream_t stream) {
    const void* h = d_in[0];
    const int* src = (const int*)d_in[1];
    const int* dst = (const int*)d_in[2];
    const void* Wt[3] = {d_in[3], d_in[5], d_in[7]};
    const void* bt[3] = {d_in[4], d_in[6], d_in[8]};

    // workspace layout (ints/floats are 4B; ~43 MB total)
    int* flags = (int*)d_ws;                        // 4
    int* degS = flags + 4;                          // 50000
    int* degD = degS + N_NODES;                     // 50000
    float* normS = (float*)(degD + N_NODES);        // 50000
    float* normD = normS + N_NODES;                 // 50000
    int* rowptr = (int*)(normD + N_NODES);          // 50001
    int* cnt = rowptr + N_NODES + 1;                // 50000
    int* esrc = cnt + N_NODES;                      // 800000
    float* A = (float*)(esrc + N_EDGES);            // 4.8M
    float* Bm = A + (size_t)N_NODES * DIM;          // 4.8M

    detect_kernel<<<1, 64, 0, stream>>>((const unsigned*)h, (const unsigned*)d_in[3],
                                        (const unsigned*)src, flags);

    hipMemsetAsync(degS, 0, 2 * N_NODES * sizeof(int), stream);
    hipMemsetAsync(cnt, 0, N_NODES * sizeof(int), stream);
    deg_kernel<<<(N_EDGES + 255) / 256, 256, 0, stream>>>(src, dst, degS, degD, flags);
    norm_kernel<<<(N_NODES + 255) / 256, 256, 0, stream>>>(degS, degD, normS, normD);
    scan_kernel<<<1, 1024, 0, stream>>>(degD, rowptr);
    bucket_kernel<<<(N_EDGES + 255) / 256, 256, 0, stream>>>(src, dst, rowptr, cnt, esrc, flags);

    cvt_kernel<<<(N_NODES * DIM + 255) / 256, 256, 0, stream>>>(h, normS, A, flags);

    const int gather_grid = (N_NODES * CH + 255) / 256;
    const int gemm_grid = (N_NODES + 63) / 64;

    for (int l = 0; l < 3; ++l) {
        gather_kernel<<<gather_grid, 256, 0, stream>>>(A, rowptr, esrc, normD, Bm);
        if (l < 2)
            gemm_relu<false><<<gemm_grid, 256, 0, stream>>>(Bm, normS, Wt[l], bt[l], A, nullptr, flags);
        else
            gemm_relu<true><<<gemm_grid, 256, 0, stream>>>(Bm, normS, Wt[l], bt[l], nullptr,
                                                           d_out, flags);
    }
}

// Round 5
// 506.370 us; speedup vs baseline: 7.7079x; 1.1374x over previous
//
#include <hip/hip_runtime.h>
#include <hip/hip_bf16.h>

#define N_NODES 50000
#define N_EDGES 800000
#define DIM 96
#define CH 24  // DIM/4 float4 chunks per row

#define SCAN_CHUNK 1024                      // elems per block in hierarchical scan
#define SCAN_NB ((N_NODES + SCAN_CHUNK - 1) / SCAN_CHUNK)  // 49

// ---------------- dtype detection (on-device, graph-capture safe) ----------------
// flags[0] = h is bf16, flags[1] = W/b are bf16, flags[2] = indices are int64
// Measured R3/R4: this problem instance is fp32 + int64; detector kept for safety.

__global__ void detect_kernel(const unsigned* __restrict__ hw,
                              const unsigned* __restrict__ ww,
                              const unsigned* __restrict__ sw,
                              int* __restrict__ flags) {
    int t = threadIdx.x;
    if (t == 0 || t == 1) {
        const unsigned* p = (t == 0) ? hw : ww;
        int good = 0;
        for (int i = 0; i < 128; ++i) {
            unsigned w = p[i];
            unsigned lo = w & 0xFFFFu, hi = w >> 16;
            unsigned e0 = (lo >> 7) & 0xFF, e1 = (hi >> 7) & 0xFF;
            if (lo == 0 || (e0 >= 100 && e0 <= 140)) ++good;
            if (hi == 0 || (e1 >= 100 && e1 <= 140)) ++good;
        }
        flags[t] = (good >= 226) ? 1 : 0;
    } else if (t == 2) {
        int zeros = 0;
        for (int i = 0; i < 64; ++i)
            if (sw[2 * i + 1] == 0u) ++zeros;
        flags[2] = (zeros >= 60) ? 1 : 0;
    }
}

__device__ __forceinline__ int load_idx(const int* __restrict__ p, int e, int is64) {
    return p[is64 ? (e << 1) : e];
}

// ---------------- degrees ----------------

__global__ __launch_bounds__(256) void deg_kernel(const int* __restrict__ src,
                                                  const int* __restrict__ dst,
                                                  int* __restrict__ degS,
                                                  int* __restrict__ degD,
                                                  const int* __restrict__ flags) {
    int is64 = flags[2];
    int e = blockIdx.x * 256 + threadIdx.x;
    if (e < N_EDGES) {
        atomicAdd(&degS[load_idx(src, e, is64)], 1);
        atomicAdd(&degD[load_idx(dst, e, is64)], 1);
    }
}

__global__ __launch_bounds__(256) void norm_kernel(const int* __restrict__ degS,
                                                   const int* __restrict__ degD,
                                                   float* __restrict__ normS,
                                                   float* __restrict__ normD) {
    int i = blockIdx.x * 256 + threadIdx.x;
    if (i < N_NODES) {
        normS[i] = rsqrtf((float)max(degS[i], 1));
        normD[i] = rsqrtf((float)max(degD[i], 1));
    }
}

// ---------------- hierarchical exclusive scan of degD -> rowptr ----------------
// pass1: 49 blocks x 256 thr x 4 elem -> block sums
// pass2: 1 wave scans 49 partials -> exclusive block offsets
// pass3: 49 blocks local-scan + add offset -> rowptr

__global__ __launch_bounds__(256) void scan_p1(const int* __restrict__ degD,
                                               int* __restrict__ psum) {
    __shared__ int red[256];
    int b = blockIdx.x, t = threadIdx.x;
    int base = b * SCAN_CHUNK + t * 4;
    int s = 0;
#pragma unroll
    for (int i = 0; i < 4; ++i) {
        int idx = base + i;
        if (idx < N_NODES) s += degD[idx];
    }
    red[t] = s;
    __syncthreads();
    for (int off = 128; off > 0; off >>= 1) {
        if (t < off) red[t] += red[t + off];
        __syncthreads();
    }
    if (t == 0) psum[b] = red[0];
}

__global__ __launch_bounds__(64) void scan_p2(const int* __restrict__ psum,
                                              int* __restrict__ poff) {
    __shared__ int s[64];
    int t = threadIdx.x;
    int v = (t < SCAN_NB) ? psum[t] : 0;
    s[t] = v;
    __syncthreads();
    for (int off = 1; off < 64; off <<= 1) {
        int u = (t >= off) ? s[t - off] : 0;
        __syncthreads();
        s[t] += u;
        __syncthreads();
    }
    if (t < SCAN_NB) poff[t] = s[t] - v;  // exclusive
}

__global__ __launch_bounds__(256) void scan_p3(const int* __restrict__ degD,
                                               const int* __restrict__ poff,
                                               int* __restrict__ rowptr) {
    __shared__ int s[256];
    int b = blockIdx.x, t = threadIdx.x;
    int base = b * SCAN_CHUNK + t * 4;
    int d[4];
    int tsum = 0;
#pragma unroll
    for (int i = 0; i < 4; ++i) {
        int idx = base + i;
        d[i] = (idx < N_NODES) ? degD[idx] : 0;
        tsum += d[i];
    }
    s[t] = tsum;
    __syncthreads();
    for (int off = 1; off < 256; off <<= 1) {
        int u = (t >= off) ? s[t - off] : 0;
        __syncthreads();
        s[t] += u;
        __syncthreads();
    }
    int run = poff[b] + s[t] - tsum;  // exclusive prefix for this thread's chunk
#pragma unroll
    for (int i = 0; i < 4; ++i) {
        int idx = base + i;
        if (idx < N_NODES) { rowptr[idx] = run; run += d[i]; }
    }
    if (b == 0 && t == 0) rowptr[N_NODES] = N_EDGES;
}

// bucket-place: esrc[rowptr[dst]+slot] = src  (1 int atomic per edge)

__global__ __launch_bounds__(256) void bucket_kernel(const int* __restrict__ src,
                                                     const int* __restrict__ dst,
                                                     const int* __restrict__ rowptr,
                                                     int* __restrict__ cnt,
                                                     int* __restrict__ esrc,
                                                     const int* __restrict__ flags) {
    int is64 = flags[2];
    int e = blockIdx.x * 256 + threadIdx.x;
    if (e < N_EDGES) {
        int d = load_idx(dst, e, is64);
        int s = load_idx(src, e, is64);
        int pos = rowptr[d] + atomicAdd(&cnt[d], 1);
        esrc[pos] = s;
    }
}

// ---------------- layer-0 input -> fp32, pre-scaled by normS ----------------

__global__ __launch_bounds__(256) void cvt_kernel(const void* __restrict__ h,
                                                  const float* __restrict__ normS,
                                                  float* __restrict__ out,
                                                  const int* __restrict__ flags) {
    int i = blockIdx.x * 256 + threadIdx.x;
    if (i >= N_NODES * DIM) return;
    float v = flags[0] ? __bfloat162float(((const __hip_bfloat16*)h)[i])
                       : ((const float*)h)[i];
    out[i] = v * normS[i / DIM];
}

// ---------------- gather: B[n] = normD[n] * sum_{e:dst=n} xs[esrc[e]] ----------------

__global__ __launch_bounds__(256) void gather_kernel(const float* __restrict__ xs,
                                                     const int* __restrict__ rowptr,
                                                     const int* __restrict__ esrc,
                                                     const float* __restrict__ normD,
                                                     float* __restrict__ B) {
    int g = blockIdx.x * 256 + threadIdx.x;
    if (g >= N_NODES * CH) return;
    int n = g / CH;
    int c = g - n * CH;
    int beg = rowptr[n], end = rowptr[n + 1];
    float4 acc = make_float4(0.f, 0.f, 0.f, 0.f);
    for (int k = beg; k < end; ++k) {
        int s = esrc[k];
        float4 v = ((const float4*)xs)[s * CH + c];
        acc.x += v.x; acc.y += v.y; acc.z += v.z; acc.w += v.w;
    }
    float nd = normD[n];
    acc.x *= nd; acc.y *= nd; acc.z *= nd; acc.w *= nd;
    ((float4*)B)[g] = acc;
}

// ---------------- GEMM: t = relu(B @ W + b); non-last: A = t*normS; last: out ----------------

template <bool LAST>
__global__ __launch_bounds__(256) void gemm_relu(const float* __restrict__ M,
                                                 const float* __restrict__ normS,
                                                 const void* __restrict__ W,
                                                 const void* __restrict__ bias,
                                                 float* __restrict__ outF,
                                                 void* __restrict__ outLast,
                                                 const int* __restrict__ flags) {
    __shared__ float Ws[DIM * DIM];
    __shared__ float Bs[64][DIM + 1];
    __shared__ float bs[DIM];

    int wbf = flags[1];
    if (wbf) {
        for (int i = threadIdx.x; i < DIM * DIM; i += 256)
            Ws[i] = __bfloat162float(((const __hip_bfloat16*)W)[i]);
        if (threadIdx.x < DIM)
            bs[threadIdx.x] = __bfloat162float(((const __hip_bfloat16*)bias)[threadIdx.x]);
    } else {
        for (int i = threadIdx.x; i < DIM * DIM; i += 256)
            Ws[i] = ((const float*)W)[i];
        if (threadIdx.x < DIM)
            bs[threadIdx.x] = ((const float*)bias)[threadIdx.x];
    }

    int row0 = blockIdx.x * 64;
    for (int i = threadIdx.x; i < 64 * CH; i += 256) {
        int r = i / CH;
        int c4 = i - r * CH;
        int gr = row0 + r;
        float4 v = make_float4(0.f, 0.f, 0.f, 0.f);
        if (gr < N_NODES) v = ((const float4*)M)[gr * CH + c4];
        float* bp = &Bs[r][c4 * 4];
        bp[0] = v.x; bp[1] = v.y; bp[2] = v.z; bp[3] = v.w;
    }
    __syncthreads();

    int cg = threadIdx.x & 7;
    int rg = threadIdx.x >> 3;
    int r0 = rg * 2;
    int c0 = cg * 12;

    float acc0[12], acc1[12];
#pragma unroll
    for (int j = 0; j < 12; ++j) { acc0[j] = 0.f; acc1[j] = 0.f; }

    for (int k = 0; k < DIM; ++k) {
        float a0 = Bs[r0][k];
        float a1 = Bs[r0 + 1][k];
        const float4* w4 = (const float4*)&Ws[k * DIM + c0];
#pragma unroll
        for (int j4 = 0; j4 < 3; ++j4) {
            float4 w = w4[j4];
            acc0[j4 * 4 + 0] += a0 * w.x;
            acc0[j4 * 4 + 1] += a0 * w.y;
            acc0[j4 * 4 + 2] += a0 * w.z;
            acc0[j4 * 4 + 3] += a0 * w.w;
            acc1[j4 * 4 + 0] += a1 * w.x;
            acc1[j4 * 4 + 1] += a1 * w.y;
            acc1[j4 * 4 + 2] += a1 * w.z;
            acc1[j4 * 4 + 3] += a1 * w.w;
        }
    }

    int hbf = flags[0];
#pragma unroll
    for (int rr = 0; rr < 2; ++rr) {
        int gr = row0 + r0 + rr;
        if (gr >= N_NODES) continue;
        const float* accp = rr ? acc1 : acc0;
        float ns = LAST ? 1.f : normS[gr];
#pragma unroll
        for (int j = 0; j < 12; ++j) {
            float v = fmaxf(accp[j] + bs[c0 + j], 0.f);
            size_t idx = (size_t)gr * DIM + c0 + j;
            if (LAST) {
                if (hbf)
                    ((__hip_bfloat16*)outLast)[idx] = __float2bfloat16(v);
                else
                    ((float*)outLast)[idx] = v;
            } else {
                outF[idx] = v * ns;
            }
        }
    }
}

// ---------------- host launch ----------------

extern "C" void kernel_launch(void* const* d_in, const int* in_sizes, int n_in,
                              void* d_out, int out_size, void* d_ws, size_t ws_size,
                              hipStream_t stream) {
    const void* h = d_in[0];
    const int* src = (const int*)d_in[1];
    const int* dst = (const int*)d_in[2];
    const void* Wt[3] = {d_in[3], d_in[5], d_in[7]};
    const void* bt[3] = {d_in[4], d_in[6], d_in[8]};

    // workspace layout (4B units)
    int* flags = (int*)d_ws;                        // 4
    int* degS = flags + 4;                          // 50000
    int* degD = degS + N_NODES;                     // 50000
    float* normS = (float*)(degD + N_NODES);        // 50000
    float* normD = normS + N_NODES;                 // 50000
    int* rowptr = (int*)(normD + N_NODES);          // 50001
    int* cnt = rowptr + N_NODES + 1;                // 50000
    int* psum = cnt + N_NODES;                      // 64
    int* poff = psum + 64;                          // 64
    int* esrc = poff + 64;                          // 800000
    float* A = (float*)(esrc + N_EDGES);            // 4.8M
    float* Bm = A + (size_t)N_NODES * DIM;          // 4.8M

    detect_kernel<<<1, 64, 0, stream>>>((const unsigned*)h, (const unsigned*)d_in[3],
                                        (const unsigned*)src, flags);

    hipMemsetAsync(degS, 0, 2 * N_NODES * sizeof(int), stream);
    hipMemsetAsync(cnt, 0, N_NODES * sizeof(int), stream);
    deg_kernel<<<(N_EDGES + 255) / 256, 256, 0, stream>>>(src, dst, degS, degD, flags);
    norm_kernel<<<(N_NODES + 255) / 256, 256, 0, stream>>>(degS, degD, normS, normD);
    scan_p1<<<SCAN_NB, 256, 0, stream>>>(degD, psum);
    scan_p2<<<1, 64, 0, stream>>>(psum, poff);
    scan_p3<<<SCAN_NB, 256, 0, stream>>>(degD, poff, rowptr);
    bucket_kernel<<<(N_EDGES + 255) / 256, 256, 0, stream>>>(src, dst, rowptr, cnt, esrc, flags);

    cvt_kernel<<<(N_NODES * DIM + 255) / 256, 256, 0, stream>>>(h, normS, A, flags);

    const int gather_grid = (N_NODES * CH + 255) / 256;
    const int gemm_grid = (N_NODES + 63) / 64;

    for (int l = 0; l < 3; ++l) {
        gather_kernel<<<gather_grid, 256, 0, stream>>>(A, rowptr, esrc, normD, Bm);
        if (l < 2)
            gemm_relu<false><<<gemm_grid, 256, 0, stream>>>(Bm, normS, Wt[l], bt[l], A, nullptr, flags);
        else
            gemm_relu<true><<<gemm_grid, 256, 0, stream>>>(Bm, normS, Wt[l], bt[l], nullptr,
                                                           d_out, flags);
    }
}